// Round 4
// baseline (102.482 us; speedup 1.0000x reference)
//
#include <hip/hip_runtime.h>
#include <math.h>

// TopologyHead: persistence image (B,64,64) + persistence landscapes (B,5,256)
// B=64, N=4096. Output = [image flat 262144][landscapes flat 81920], fp32.
//
// 2 graph nodes:
//  hipMemsetAsync : zero 128 per-batch completion counters (512 B)
//  k_main (768 blocks):
//    blocks [0,256)   image: bf16 MFMA K-split GEMM (KC=4); last block of each
//                     batch (atomic counter) sums partials + max + normalize.
//    blocks [256,768) landscapes: in-block batch minmax, top-5 tent partials
//                     (med3 insert, wave-uniform point loads), 4-wave LDS
//                     pre-merge; last block of each batch merges 8 lists.

#define B_   64
#define N_   4096
#define HW_  64
#define RES_ 256
#define EPSF 1e-8f
#define KC_  4          // image K-split (1024 points per img block)
#define CPB  1024       // points per image block
#define KP   64         // points per staged LDS chunk (img)
#define LPB_ 8          // landscape blocks per batch
#define LCH  128        // points per landscape wave chunk

typedef short short8v  __attribute__((ext_vector_type(8)));
typedef float float4v  __attribute__((ext_vector_type(4)));

__device__ __forceinline__ unsigned short f2bf(float f) {
    unsigned int u = __float_as_uint(f);
    u += 0x7fffu + ((u >> 16) & 1u);          // round-nearest-even
    return (unsigned short)(u >> 16);
}

// sorted-desc 5-list insert, 5 ops via med3; x<0 is a no-op (list >= 0)
#define INS5(v0, v1, v2, v3, v4, x)                       \
    {                                                     \
        float _p0 = v0, _p1 = v1, _p2 = v2, _p3 = v3;     \
        v0 = fmaxf(_p0, x);                               \
        v1 = __builtin_amdgcn_fmed3f(_p0, _p1, x);        \
        v2 = __builtin_amdgcn_fmed3f(_p1, _p2, x);        \
        v3 = __builtin_amdgcn_fmed3f(_p2, _p3, x);        \
        v4 = __builtin_amdgcn_fmed3f(_p3, v4, x);         \
    }

union SmemU {
    struct {                                   // image path (26.6 KB)
        unsigned short gy[64 * 72];
        unsigned short gx[64 * 72];
        float2 pts[CPB];
    } img;
    struct {                                   // landscape path (20.5 KB)
        float lmerge[4 * 5 * RES_];
        float red[8];
    } land;
};

__global__ __launch_bounds__(256) void k_main(const float* __restrict__ pairs,
                                              const float* __restrict__ sigp,
                                              float* __restrict__ part,
                                              float* __restrict__ lp,
                                              int* __restrict__ ctr,
                                              float* __restrict__ out) {
    __shared__ SmemU sm;
    __shared__ int last_flag;
    __shared__ float redf[4];

    int tid = threadIdx.x;
    int l = tid & 63, w = tid >> 6;

    if (blockIdx.x < 256) {
        // ================= image path =================
        int kc = blockIdx.x & 3, b = blockIdx.x >> 2;
        float sigma = sigp[0];
        float cc = 0.5f / (sigma * sigma);

        const float4* src = (const float4*)(pairs + 2 * ((size_t)b * N_ + kc * CPB));
        ((float4*)sm.img.pts)[tid]       = src[tid];
        ((float4*)sm.img.pts)[256 + tid] = src[256 + tid];

        int c  = tid & 63;              // coordinate this thread stages
        int pg = tid >> 6;              // point sub-group
        float xc = (float)c * (1.0f / 63.0f);

        float4v acc[4];
        #pragma unroll
        for (int c4 = 0; c4 < 4; ++c4) acc[c4] = (float4v){0.f, 0.f, 0.f, 0.f};

        int rowA = (w * 16 + (l & 15)) * 72 + (l >> 4) * 8;

        for (int ch = 0; ch < CPB / KP; ++ch) {
            __syncthreads();
            int p0 = ch * KP + pg * 16;
            alignas(16) unsigned short gyb[16], gxb[16];
            #pragma unroll
            for (int j = 0; j < 16; ++j) {
                float2 q = sm.img.pts[p0 + j];
                float pe = q.y - q.x;
                float dx = xc - q.x;
                float dy = xc - pe;
                gxb[j] = f2bf(__expf(-dx * dx * cc));
                gyb[j] = f2bf(pe * __expf(-dy * dy * cc));
            }
            *(uint4*)&sm.img.gy[c * 72 + pg * 16]     = *(uint4*)&gyb[0];
            *(uint4*)&sm.img.gy[c * 72 + pg * 16 + 8] = *(uint4*)&gyb[8];
            *(uint4*)&sm.img.gx[c * 72 + pg * 16]     = *(uint4*)&gxb[0];
            *(uint4*)&sm.img.gx[c * 72 + pg * 16 + 8] = *(uint4*)&gxb[8];
            __syncthreads();
            #pragma unroll
            for (int ks = 0; ks < 2; ++ks) {
                short8v af = *(const short8v*)&sm.img.gy[rowA + ks * 32];
                #pragma unroll
                for (int c4 = 0; c4 < 4; ++c4) {
                    short8v bf = *(const short8v*)
                        &sm.img.gx[(c4 * 16 + (l & 15)) * 72 + ks * 32 + (l >> 4) * 8];
                    acc[c4] = __builtin_amdgcn_mfma_f32_16x16x32_bf16(af, bf, acc[c4], 0, 0, 0);
                }
            }
        }

        // write this block's partial (C/D layout: col=lane&15, row=(lane>>4)*4+reg)
        float* dst = part + (size_t)(b * KC_ + kc) * (HW_ * HW_);
        #pragma unroll
        for (int c4 = 0; c4 < 4; ++c4)
            #pragma unroll
            for (int reg = 0; reg < 4; ++reg) {
                int h = w * 16 + (l >> 4) * 4 + reg;
                int wv = c4 * 16 + (l & 15);
                dst[h * HW_ + wv] = acc[c4][reg];
            }

        __syncthreads();                       // drains vmcnt: partial is in L2
        if (tid == 0) {
            int old = __hip_atomic_fetch_add(&ctr[b], 1, __ATOMIC_ACQ_REL,
                                             __HIP_MEMORY_SCOPE_AGENT);
            last_flag = (old == KC_ - 1);
        }
        __syncthreads();
        if (last_flag) {
            // ---- per-batch image finish: sum 4 partials, max, normalize ----
            const float4* p0 = (const float4*)(part + (size_t)b * KC_ * (HW_ * HW_));
            float4 s[4];
            float m = 0.0f;
            #pragma unroll
            for (int i = 0; i < 4; ++i) {
                int pix4 = tid + i * 256;
                float4 v = p0[pix4];
                #pragma unroll
                for (int k2 = 1; k2 < KC_; ++k2) {
                    float4 u = p0[(size_t)k2 * 1024 + pix4];
                    v.x += u.x; v.y += u.y; v.z += u.z; v.w += u.w;
                }
                s[i] = v;
                m = fmaxf(m, fmaxf(fmaxf(v.x, v.y), fmaxf(v.z, v.w)));
            }
            #pragma unroll
            for (int off = 32; off > 0; off >>= 1) m = fmaxf(m, __shfl_xor(m, off, 64));
            if ((tid & 63) == 0) redf[tid >> 6] = m;
            __syncthreads();
            m = fmaxf(fmaxf(redf[0], redf[1]), fmaxf(redf[2], redf[3]));
            float inv = 1.0f / (m + EPSF);
            float4* od = (float4*)(out + (size_t)b * (HW_ * HW_));
            #pragma unroll
            for (int i = 0; i < 4; ++i) {
                float4 v = s[i];
                v.x *= inv; v.y *= inv; v.z *= inv; v.w *= inv;
                od[tid + i * 256] = v;
            }
        }
    } else {
        // ================= landscape path =================
        int idx = blockIdx.x - 256;            // 0..511
        int b = idx >> 3, pcb = idx & 7;

        // ---- phase 0: in-block batch min/max (32 KB, L2-hot) ----
        const float4* pb4 = (const float4*)(pairs + 2 * (size_t)b * N_);
        float mn = 1e30f, mx = -1e30f;
        #pragma unroll
        for (int i = 0; i < 8; ++i) {
            float4 q = pb4[tid + i * 256];
            mn = fminf(mn, fminf(q.x, q.z));
            mx = fmaxf(mx, fmaxf(q.y, q.w));
        }
        #pragma unroll
        for (int off = 32; off > 0; off >>= 1) {
            mn = fminf(mn, __shfl_xor(mn, off, 64));
            mx = fmaxf(mx, __shfl_xor(mx, off, 64));
        }
        if ((tid & 63) == 0) { sm.land.red[w] = mn; sm.land.red[4 + w] = mx; }
        __syncthreads();
        float minb = fminf(fminf(sm.land.red[0], sm.land.red[1]),
                           fminf(sm.land.red[2], sm.land.red[3]));
        float maxd = fmaxf(fmaxf(sm.land.red[4], sm.land.red[5]),
                           fmaxf(sm.land.red[6], sm.land.red[7]));

        // ---- phase 1: top-5 tents, wave w handles chunk pc = pcb*4+w ----
        int pc = pcb * 4 + w;
        float scl = (maxd - minb) * (1.0f / 255.0f);
        float t0 = minb + scl * (float)l;
        float t1 = t0 + scl * 64.0f;
        float t2 = t0 + scl * 128.0f;
        float t3 = t0 + scl * 192.0f;

        float a0 = 0.f, a1 = 0.f, a2 = 0.f, a3 = 0.f, a4 = 0.f;
        float b0 = 0.f, b1 = 0.f, b2 = 0.f, b3 = 0.f, b4 = 0.f;
        float c0 = 0.f, c1 = 0.f, c2 = 0.f, c3 = 0.f, c4 = 0.f;
        float d0 = 0.f, d1 = 0.f, d2 = 0.f, d3 = 0.f, d4 = 0.f;

        const float4* pw = (const float4*)(pairs + 2 * ((size_t)b * N_ + pc * LCH));
        #pragma unroll 4
        for (int p = 0; p < LCH / 2; ++p) {
            float4 q = pw[p];                  // wave-uniform, 2 points
            {
                float bb = q.x, dd = q.y;
                float x;
                x = fminf(t0 - bb, dd - t0); INS5(a0, a1, a2, a3, a4, x);
                x = fminf(t1 - bb, dd - t1); INS5(b0, b1, b2, b3, b4, x);
                x = fminf(t2 - bb, dd - t2); INS5(c0, c1, c2, c3, c4, x);
                x = fminf(t3 - bb, dd - t3); INS5(d0, d1, d2, d3, d4, x);
            }
            {
                float bb = q.z, dd = q.w;
                float x;
                x = fminf(t0 - bb, dd - t0); INS5(a0, a1, a2, a3, a4, x);
                x = fminf(t1 - bb, dd - t1); INS5(b0, b1, b2, b3, b4, x);
                x = fminf(t2 - bb, dd - t2); INS5(c0, c1, c2, c3, c4, x);
                x = fminf(t3 - bb, dd - t3); INS5(d0, d1, d2, d3, d4, x);
            }
        }

        // ---- phase 2: 4-wave LDS pre-merge -> one list per block ----
        __syncthreads();                       // red[] reads done before reuse
        float* lm = sm.land.lmerge;
        lm[(w * 5 + 0) * RES_ + l]       = a0; lm[(w * 5 + 1) * RES_ + l]       = a1;
        lm[(w * 5 + 2) * RES_ + l]       = a2; lm[(w * 5 + 3) * RES_ + l]       = a3;
        lm[(w * 5 + 4) * RES_ + l]       = a4;
        lm[(w * 5 + 0) * RES_ + l + 64]  = b0; lm[(w * 5 + 1) * RES_ + l + 64]  = b1;
        lm[(w * 5 + 2) * RES_ + l + 64]  = b2; lm[(w * 5 + 3) * RES_ + l + 64]  = b3;
        lm[(w * 5 + 4) * RES_ + l + 64]  = b4;
        lm[(w * 5 + 0) * RES_ + l + 128] = c0; lm[(w * 5 + 1) * RES_ + l + 128] = c1;
        lm[(w * 5 + 2) * RES_ + l + 128] = c2; lm[(w * 5 + 3) * RES_ + l + 128] = c3;
        lm[(w * 5 + 4) * RES_ + l + 128] = c4;
        lm[(w * 5 + 0) * RES_ + l + 192] = d0; lm[(w * 5 + 1) * RES_ + l + 192] = d1;
        lm[(w * 5 + 2) * RES_ + l + 192] = d2; lm[(w * 5 + 3) * RES_ + l + 192] = d3;
        lm[(w * 5 + 4) * RES_ + l + 192] = d4;
        __syncthreads();

        float v0 = lm[0 * RES_ + tid], v1 = lm[1 * RES_ + tid], v2 = lm[2 * RES_ + tid],
              v3 = lm[3 * RES_ + tid], v4 = lm[4 * RES_ + tid];
        #pragma unroll
        for (int wv = 1; wv < 4; ++wv)
            #pragma unroll
            for (int lvl = 0; lvl < 5; ++lvl) {
                float x = lm[(wv * 5 + lvl) * RES_ + tid];
                INS5(v0, v1, v2, v3, v4, x);
            }
        float* dl = lp + (size_t)(b * LPB_ + pcb) * 5 * RES_;
        dl[0 * RES_ + tid] = v0; dl[1 * RES_ + tid] = v1; dl[2 * RES_ + tid] = v2;
        dl[3 * RES_ + tid] = v3; dl[4 * RES_ + tid] = v4;

        __syncthreads();                       // drains vmcnt: lp lists in L2
        if (tid == 0) {
            int old = __hip_atomic_fetch_add(&ctr[64 + b], 1, __ATOMIC_ACQ_REL,
                                             __HIP_MEMORY_SCOPE_AGENT);
            last_flag = (old == LPB_ - 1);
        }
        __syncthreads();
        if (last_flag) {
            // ---- per-batch landscape finish: merge 8 lists per r = tid ----
            const float* lpb = lp + (size_t)b * LPB_ * 5 * RES_;
            float u0 = lpb[0 * RES_ + tid], u1 = lpb[1 * RES_ + tid],
                  u2 = lpb[2 * RES_ + tid], u3 = lpb[3 * RES_ + tid],
                  u4 = lpb[4 * RES_ + tid];
            for (int p2 = 1; p2 < LPB_; ++p2) {
                #pragma unroll
                for (int lvl = 0; lvl < 5; ++lvl) {
                    float x = lpb[(p2 * 5 + lvl) * RES_ + tid];
                    INS5(u0, u1, u2, u3, u4, x);
                }
            }
            float* o = out + (size_t)B_ * HW_ * HW_ + (size_t)b * (5 * RES_);
            o[tid]            = u0;
            o[RES_ + tid]     = u1;
            o[2 * RES_ + tid] = u2;
            o[3 * RES_ + tid] = u3;
            o[4 * RES_ + tid] = u4;
        }
    }
}

extern "C" void kernel_launch(void* const* d_in, const int* in_sizes, int n_in,
                              void* d_out, int out_size, void* d_ws, size_t ws_size,
                              hipStream_t stream) {
    const float* pairs = (const float*)d_in[0];
    const float* sig   = (const float*)d_in[1];
    float* out = (float*)d_out;
    float* wsf = (float*)d_ws;

    // ws layout: [0..127] int counters | part (B*KC*4096 = 4 MB) | lp (B*8*5*256 = 2.6 MB)
    int*   ctr  = (int*)wsf;
    float* part = wsf + 128;
    float* lp   = part + (size_t)B_ * KC_ * HW_ * HW_;

    hipMemsetAsync(ctr, 0, 128 * sizeof(int), stream);
    k_main<<<768, 256, 0, stream>>>(pairs, sig, part, lp, ctr, out);
}

// Round 5
// 98.331 us; speedup vs baseline: 1.0422x; 1.0422x over previous
//
#include <hip/hip_runtime.h>
#include <math.h>

// TopologyHead: persistence image (B,64,64) + persistence landscapes (B,5,256)
// B=64, N=4096. Output = [image flat 262144][landscapes flat 81920], fp32.
//
// 2 graph nodes (no atomics — R4's agent-scope ACQ_REL per block forced
// cross-XCD L2 writeback/invalidate x768, +16us; a kernel boundary is ONE fence):
//  k_partial (1536 blocks, role = blockIdx%3):
//    role 0 (512): image bf16-MFMA K-split GEMM (KC=8, 512 pts/block)
//    role 1,2 (1024): landscape: in-block batch minmax, top-5 tents
//                     (med3 insert), 4-wave LDS pre-merge -> 16 lists/batch
//  k_finish (128 blocks): 64x image sum/max/normalize + 64x landscape merge

#define B_   64
#define N_   4096
#define HW_  64
#define RES_ 256
#define EPSF 1e-8f
#define KC_  8          // image K-split (512 points per img block)
#define CPB  512        // points per image block
#define KP   64         // points per staged chunk (img)
#define LPB_ 16         // landscape blocks per batch
#define LCH  64         // points per landscape wave chunk

typedef short short8v  __attribute__((ext_vector_type(8)));
typedef float float4v  __attribute__((ext_vector_type(4)));

// pack two f32 -> bf16x2, round-half-up (<=0.5 ulp, like RNE except ties)
__device__ __forceinline__ unsigned pk_bf(float a, float b) {
    unsigned ua = __float_as_uint(a), ub = __float_as_uint(b);
    return ((ua + 0x8000u) >> 16) | ((ub + 0x8000u) & 0xffff0000u);
}

// sorted-desc 5-list insert, 5 ops via med3; x<0 is a no-op (list >= 0)
#define INS5(v0, v1, v2, v3, v4, x)                       \
    {                                                     \
        float _p0 = v0, _p1 = v1, _p2 = v2, _p3 = v3;     \
        v0 = fmaxf(_p0, x);                               \
        v1 = __builtin_amdgcn_fmed3f(_p0, _p1, x);        \
        v2 = __builtin_amdgcn_fmed3f(_p1, _p2, x);        \
        v3 = __builtin_amdgcn_fmed3f(_p2, _p3, x);        \
        v4 = __builtin_amdgcn_fmed3f(_p3, v4, x);         \
    }

union SmemU {
    struct {                                   // image path (18.4 KB)
        unsigned short gy[64 * 72];
        unsigned short gx[64 * 72];
    } img;
    struct {                                   // landscape path (20.5 KB)
        float lmerge[4 * 5 * RES_];
        float red[8];
    } land;
};

__global__ __launch_bounds__(256) void k_partial(const float* __restrict__ pairs,
                                                 const float* __restrict__ sigp,
                                                 float* __restrict__ part,
                                                 float* __restrict__ lp) {
    __shared__ SmemU sm;
    int tid = threadIdx.x;
    int l = tid & 63, w = tid >> 6;
    int role = blockIdx.x % 3;
    int id   = blockIdx.x / 3;                 // 0..511

    if (role == 0) {
        // ================= image path =================
        int kc = id & 7, b = id >> 3;
        float sigma = sigp[0];
        float ncc2 = -(0.5f / (sigma * sigma)) * 1.4426950408889634f;

        int c  = tid & 63;              // coordinate this thread stages
        int pg = tid >> 6;              // point sub-group (== wave)
        float xc = (float)c * (1.0f / 63.0f);

        float4v acc[4];
        #pragma unroll
        for (int c4 = 0; c4 < 4; ++c4) acc[c4] = (float4v){0.f, 0.f, 0.f, 0.f};

        int rowA = (w * 16 + (l & 15)) * 72 + (l >> 4) * 8;
        // float4 = 2 points; this block's 512 points
        const float4* pb4 = (const float4*)(pairs + 2 * ((size_t)b * N_ + kc * CPB));

        for (int ch = 0; ch < CPB / KP; ++ch) {   // 8 chunks of 64 points
            // ---- stage in registers (no LDS involved yet) ----
            int p0 = ch * 32 + pg * 8;            // float4 index: 16 points/thread
            unsigned gxp[8], gyp[8];
            #pragma unroll
            for (int jp = 0; jp < 8; ++jp) {
                float4 q = pb4[p0 + jp];          // wave-uniform, L1-hot
                float pe0 = q.y - q.x, pe1 = q.w - q.z;
                float dx0 = xc - q.x, dx1 = xc - q.z;
                float dy0 = xc - pe0, dy1 = xc - pe1;
                float ex0 = __builtin_amdgcn_exp2f(dx0 * dx0 * ncc2);
                float ex1 = __builtin_amdgcn_exp2f(dx1 * dx1 * ncc2);
                float ey0 = pe0 * __builtin_amdgcn_exp2f(dy0 * dy0 * ncc2);
                float ey1 = pe1 * __builtin_amdgcn_exp2f(dy1 * dy1 * ncc2);
                gxp[jp] = pk_bf(ex0, ex1);
                gyp[jp] = pk_bf(ey0, ey1);
            }
            __syncthreads();                      // prior MFMA reads done
            *(uint4*)&sm.img.gy[c * 72 + pg * 16]     = *(uint4*)&gyp[0];
            *(uint4*)&sm.img.gy[c * 72 + pg * 16 + 8] = *(uint4*)&gyp[4];
            *(uint4*)&sm.img.gx[c * 72 + pg * 16]     = *(uint4*)&gxp[0];
            *(uint4*)&sm.img.gx[c * 72 + pg * 16 + 8] = *(uint4*)&gxp[4];
            __syncthreads();
            // ---- MFMA: 2 k-steps of 32 points, 4 col-tiles each ----
            #pragma unroll
            for (int ks = 0; ks < 2; ++ks) {
                short8v af = *(const short8v*)&sm.img.gy[rowA + ks * 32];
                #pragma unroll
                for (int c4 = 0; c4 < 4; ++c4) {
                    short8v bf = *(const short8v*)
                        &sm.img.gx[(c4 * 16 + (l & 15)) * 72 + ks * 32 + (l >> 4) * 8];
                    acc[c4] = __builtin_amdgcn_mfma_f32_16x16x32_bf16(af, bf, acc[c4], 0, 0, 0);
                }
            }
        }

        // C/D layout: col=lane&15, row=(lane>>4)*4+reg
        float* dst = part + (size_t)(b * KC_ + kc) * (HW_ * HW_);
        #pragma unroll
        for (int c4 = 0; c4 < 4; ++c4)
            #pragma unroll
            for (int reg = 0; reg < 4; ++reg) {
                int h = w * 16 + (l >> 4) * 4 + reg;
                int wv = c4 * 16 + (l & 15);
                dst[h * HW_ + wv] = acc[c4][reg];
            }
    } else {
        // ================= landscape path =================
        int idx = id * 2 + (role - 1);         // 0..1023
        int b = idx >> 4, pcb = idx & 15;

        // ---- phase 0: in-block batch min/max (32 KB, L2-hot) ----
        const float4* pb4 = (const float4*)(pairs + 2 * (size_t)b * N_);
        float mn = 1e30f, mx = -1e30f;
        #pragma unroll
        for (int i = 0; i < 8; ++i) {
            float4 q = pb4[tid + i * 256];
            mn = fminf(mn, fminf(q.x, q.z));
            mx = fmaxf(mx, fmaxf(q.y, q.w));
        }
        #pragma unroll
        for (int off = 32; off > 0; off >>= 1) {
            mn = fminf(mn, __shfl_xor(mn, off, 64));
            mx = fmaxf(mx, __shfl_xor(mx, off, 64));
        }
        if ((tid & 63) == 0) { sm.land.red[w] = mn; sm.land.red[4 + w] = mx; }
        __syncthreads();
        float minb = fminf(fminf(sm.land.red[0], sm.land.red[1]),
                           fminf(sm.land.red[2], sm.land.red[3]));
        float maxd = fmaxf(fmaxf(sm.land.red[4], sm.land.red[5]),
                           fmaxf(sm.land.red[6], sm.land.red[7]));

        // ---- phase 1: top-5 tents, wave w -> chunk pc = pcb*4+w (64 pts) ----
        int pc = pcb * 4 + w;
        float scl = (maxd - minb) * (1.0f / 255.0f);
        float t0 = minb + scl * (float)l;
        float t1 = t0 + scl * 64.0f;
        float t2 = t0 + scl * 128.0f;
        float t3 = t0 + scl * 192.0f;

        float a0 = 0.f, a1 = 0.f, a2 = 0.f, a3 = 0.f, a4 = 0.f;
        float b0 = 0.f, b1 = 0.f, b2 = 0.f, b3 = 0.f, b4 = 0.f;
        float c0 = 0.f, c1 = 0.f, c2 = 0.f, c3 = 0.f, c4 = 0.f;
        float d0 = 0.f, d1 = 0.f, d2 = 0.f, d3 = 0.f, d4 = 0.f;

        const float4* pw = (const float4*)(pairs + 2 * ((size_t)b * N_ + pc * LCH));
        #pragma unroll 4
        for (int p = 0; p < LCH / 2; ++p) {
            float4 q = pw[p];                  // wave-uniform, 2 points
            {
                float bb = q.x, dd = q.y;
                float x;
                x = fminf(t0 - bb, dd - t0); INS5(a0, a1, a2, a3, a4, x);
                x = fminf(t1 - bb, dd - t1); INS5(b0, b1, b2, b3, b4, x);
                x = fminf(t2 - bb, dd - t2); INS5(c0, c1, c2, c3, c4, x);
                x = fminf(t3 - bb, dd - t3); INS5(d0, d1, d2, d3, d4, x);
            }
            {
                float bb = q.z, dd = q.w;
                float x;
                x = fminf(t0 - bb, dd - t0); INS5(a0, a1, a2, a3, a4, x);
                x = fminf(t1 - bb, dd - t1); INS5(b0, b1, b2, b3, b4, x);
                x = fminf(t2 - bb, dd - t2); INS5(c0, c1, c2, c3, c4, x);
                x = fminf(t3 - bb, dd - t3); INS5(d0, d1, d2, d3, d4, x);
            }
        }

        // ---- phase 2: 4-wave LDS pre-merge -> one list per block ----
        float* lm = sm.land.lmerge;
        lm[(w * 5 + 0) * RES_ + l]       = a0; lm[(w * 5 + 1) * RES_ + l]       = a1;
        lm[(w * 5 + 2) * RES_ + l]       = a2; lm[(w * 5 + 3) * RES_ + l]       = a3;
        lm[(w * 5 + 4) * RES_ + l]       = a4;
        lm[(w * 5 + 0) * RES_ + l + 64]  = b0; lm[(w * 5 + 1) * RES_ + l + 64]  = b1;
        lm[(w * 5 + 2) * RES_ + l + 64]  = b2; lm[(w * 5 + 3) * RES_ + l + 64]  = b3;
        lm[(w * 5 + 4) * RES_ + l + 64]  = b4;
        lm[(w * 5 + 0) * RES_ + l + 128] = c0; lm[(w * 5 + 1) * RES_ + l + 128] = c1;
        lm[(w * 5 + 2) * RES_ + l + 128] = c2; lm[(w * 5 + 3) * RES_ + l + 128] = c3;
        lm[(w * 5 + 4) * RES_ + l + 128] = c4;
        lm[(w * 5 + 0) * RES_ + l + 192] = d0; lm[(w * 5 + 1) * RES_ + l + 192] = d1;
        lm[(w * 5 + 2) * RES_ + l + 192] = d2; lm[(w * 5 + 3) * RES_ + l + 192] = d3;
        lm[(w * 5 + 4) * RES_ + l + 192] = d4;
        __syncthreads();

        float v0 = lm[0 * RES_ + tid], v1 = lm[1 * RES_ + tid], v2 = lm[2 * RES_ + tid],
              v3 = lm[3 * RES_ + tid], v4 = lm[4 * RES_ + tid];
        #pragma unroll
        for (int wv = 1; wv < 4; ++wv)
            #pragma unroll
            for (int lvl = 0; lvl < 5; ++lvl) {
                float x = lm[(wv * 5 + lvl) * RES_ + tid];
                INS5(v0, v1, v2, v3, v4, x);
            }
        float* dl = lp + (size_t)(b * LPB_ + pcb) * 5 * RES_;
        dl[0 * RES_ + tid] = v0; dl[1 * RES_ + tid] = v1; dl[2 * RES_ + tid] = v2;
        dl[3 * RES_ + tid] = v3; dl[4 * RES_ + tid] = v4;
    }
}

// ---------------- finish: image sum/max/normalize + landscape merge ----------------
__global__ __launch_bounds__(256) void k_finish(const float* __restrict__ part,
                                                const float* __restrict__ lp,
                                                float* __restrict__ out) {
    __shared__ float redf[4];
    int tid = threadIdx.x;
    if (blockIdx.x < 64) {
        int b = blockIdx.x;
        const float4* p0 = (const float4*)(part + (size_t)b * KC_ * (HW_ * HW_));
        float4 s[4];
        float m = 0.0f;
        #pragma unroll
        for (int i = 0; i < 4; ++i) {
            int pix4 = tid + i * 256;
            float4 v = p0[pix4];
            #pragma unroll
            for (int k2 = 1; k2 < KC_; ++k2) {
                float4 u = p0[(size_t)k2 * 1024 + pix4];
                v.x += u.x; v.y += u.y; v.z += u.z; v.w += u.w;
            }
            s[i] = v;
            m = fmaxf(m, fmaxf(fmaxf(v.x, v.y), fmaxf(v.z, v.w)));
        }
        #pragma unroll
        for (int off = 32; off > 0; off >>= 1) m = fmaxf(m, __shfl_xor(m, off, 64));
        if ((tid & 63) == 0) redf[tid >> 6] = m;
        __syncthreads();
        m = fmaxf(fmaxf(redf[0], redf[1]), fmaxf(redf[2], redf[3]));
        float inv = 1.0f / (m + EPSF);
        float4* od = (float4*)(out + (size_t)b * (HW_ * HW_));
        #pragma unroll
        for (int i = 0; i < 4; ++i) {
            float4 v = s[i];
            v.x *= inv; v.y *= inv; v.z *= inv; v.w *= inv;
            od[tid + i * 256] = v;
        }
    } else {
        int b = blockIdx.x - 64;
        const float* lpb = lp + (size_t)b * LPB_ * 5 * RES_;
        float u0 = lpb[0 * RES_ + tid], u1 = lpb[1 * RES_ + tid],
              u2 = lpb[2 * RES_ + tid], u3 = lpb[3 * RES_ + tid],
              u4 = lpb[4 * RES_ + tid];
        for (int p2 = 1; p2 < LPB_; ++p2) {
            #pragma unroll
            for (int lvl = 0; lvl < 5; ++lvl) {
                float x = lpb[(p2 * 5 + lvl) * RES_ + tid];
                INS5(u0, u1, u2, u3, u4, x);
            }
        }
        float* o = out + (size_t)B_ * HW_ * HW_ + (size_t)b * (5 * RES_);
        o[tid]            = u0;
        o[RES_ + tid]     = u1;
        o[2 * RES_ + tid] = u2;
        o[3 * RES_ + tid] = u3;
        o[4 * RES_ + tid] = u4;
    }
}

extern "C" void kernel_launch(void* const* d_in, const int* in_sizes, int n_in,
                              void* d_out, int out_size, void* d_ws, size_t ws_size,
                              hipStream_t stream) {
    const float* pairs = (const float*)d_in[0];
    const float* sig   = (const float*)d_in[1];
    float* out = (float*)d_out;
    float* wsf = (float*)d_ws;

    // ws layout (floats): part (B*KC*4096 = 2M) | lp (B*16*5*256 = 5.24M)
    float* part = wsf;
    float* lp   = part + (size_t)B_ * KC_ * HW_ * HW_;

    k_partial<<<1536, 256, 0, stream>>>(pairs, sig, part, lp);
    k_finish<<<128, 256, 0, stream>>>(part, lp, out);
}